// Round 10
// baseline (173.106 us; speedup 1.0000x reference)
//
#include <hip/hip_runtime.h>

#define GG 256
#define PP 512
#define FF 4
#define KK 6
#define NN (GG*PP)

__device__ __forceinline__ unsigned umin_(unsigned a, unsigned b){ return a<b?a:b; }
__device__ __forceinline__ unsigned umax_(unsigned a, unsigned b){ return a>b?a:b; }
__device__ __forceinline__ float finf(){ return __int_as_float(0x7f800000); }

// monotone (order-preserving) map fp32 -> u32 (all non-NaN)
__device__ __forceinline__ unsigned mmap32(float d){
    int bb = __float_as_int(d);
    int t = bb >> 31;
    return (unsigned)(bb ^ (t | (int)0x80000000));
}

// u64 sorted-desc cascade (B[0] = worst of 6). Caller guarantees kv < B[0].
__device__ __forceinline__ void cas6_u64(uint64_t (&B)[6], uint64_t kv)
{
    bool c1 = kv < B[1]; bool c2 = kv < B[2]; bool c3 = kv < B[3];
    bool c4 = kv < B[4]; bool c5 = kv < B[5];
    B[0] = c1 ? B[1] : kv;
    B[1] = c2 ? B[2] : (c1 ? kv : B[1]);
    B[2] = c3 ? B[3] : (c2 ? kv : B[2]);
    B[3] = c4 ? B[4] : (c3 ? kv : B[3]);
    B[4] = c5 ? B[5] : (c4 ? kv : B[4]);
    B[5] = c5 ? kv : B[5];
}

// ascending 7-slot branchless insert on u32
#define INS7U(v){                                  \
    unsigned n0=umin_(M0,(v));                     \
    unsigned n1=umin_(M1,umax_((v),M0));           \
    unsigned n2=umin_(M2,umax_((v),M1));           \
    unsigned n3=umin_(M3,umax_((v),M2));           \
    unsigned n4=umin_(M4,umax_((v),M3));           \
    unsigned n5=umin_(M5,umax_((v),M4));           \
    unsigned n6=umin_(M6,umax_((v),M5));           \
    M0=n0;M1=n1;M2=n2;M3=n3;M4=n4;M5=n5;M6=n6; }

__global__ __launch_bounds__(512, 4) void scan_kernel(
    const float* __restrict__ x,
    const float* __restrict__ pre_W1, const float* __restrict__ pre_b1, const float* __restrict__ pre_a1,
    const float* __restrict__ pre_W2, const float* __restrict__ pre_b2, const float* __restrict__ pre_a2,
    float* __restrict__ bn_part,     // [8][G]
    int* __restrict__ knn_idx)       // [K][N]
{
    __shared__ float4   xm2s[PP];        // -2*x      (8 KB)
    __shared__ float    sqs[PP];         // |x|^2     (2 KB)
    __shared__ ushort   gmp16[32][128];  // group-min u16 [group][target] (8 KB)
    __shared__ uint64_t pairbuf[128][6]; // odd-member partial top-6 (6 KB)
    __shared__ float    wred[8][8];

    const int t = threadIdx.x;
    const int bid = blockIdx.x;
    const int g = bid >> 2, quarter = bid & 3;   // 4 blocks per graph
    const int tbase = quarter * 128;             // this block's 128 targets
    const int gbase = g * PP;
    const int w = t >> 6, lane = t & 63;
    const int wu = __builtin_amdgcn_readfirstlane(w);   // scanner id (wave-uniform)
    const int qb = wu * 64;                             // candidate base

    // ---- stage graph (+ BN partials on quarter-0 blocks) ----
    float4 xt = ((const float4*)x)[gbase + t];
    xm2s[t] = make_float4(-2.0f*xt.x, -2.0f*xt.y, -2.0f*xt.z, -2.0f*xt.w);
    sqs[t]  = xt.x*xt.x + xt.y*xt.y + xt.z*xt.z + xt.w*xt.w;
    if (quarter == 0){
        float h1[FF], h2[FF];
#pragma unroll
        for (int fo=0;fo<FF;fo++){
            float m = xt.x*pre_W1[0*FF+fo] + xt.y*pre_W1[1*FF+fo]
                    + xt.z*pre_W1[2*FF+fo] + xt.w*pre_W1[3*FF+fo] + pre_b1[fo];
            h1[fo] = m >= 0.0f ? m : pre_a1[fo]*m;
        }
#pragma unroll
        for (int fo=0;fo<FF;fo++){
            float m = h1[0]*pre_W2[0*FF+fo] + h1[1]*pre_W2[1*FF+fo]
                    + h1[2]*pre_W2[2*FF+fo] + h1[3]*pre_W2[3*FF+fo] + pre_b2[fo];
            h2[fo] = m >= 0.0f ? m : pre_a2[fo]*m;
        }
        float v[8];
#pragma unroll
        for (int f=0;f<4;f++){ v[f]=h2[f]; v[4+f]=h2[f]*h2[f]; }
#pragma unroll
        for (int off=32; off; off>>=1){
#pragma unroll
            for (int f=0;f<8;f++) v[f] += __shfl_down(v[f], off);
        }
        if (lane==0){
#pragma unroll
            for (int f=0;f<8;f++) wred[w][f]=v[f];
        }
    }
    __syncthreads();
    if (quarter == 0 && t < 8){
        float a=0;
#pragma unroll
        for (int w2=0;w2<8;w2++) a += wred[w2][t];
        bn_part[t*GG + g] = a;
    }

    // ---- 2 targets per thread in registers (lt = lane + 64j) ----
    float4 xp[2];
#pragma unroll
    for (int j=0;j<2;j++){
        float4 v = xm2s[tbase + lane + 64*j];
        xp[j] = make_float4(-0.5f*v.x, -0.5f*v.y, -0.5f*v.z, -0.5f*v.w);
    }
    const float INF = finf();

    // ---- phase 1: group minima (4 groups of 16 cands per scanner) ----
    // shifted d = |q|^2 - 2 q.p ; self = -|p|^2 = strict global min (no self test)
#pragma unroll 1
    for (int grp=0; grp<4; grp++){
        float gm[2];
        gm[0]=INF; gm[1]=INF;
#pragma unroll
        for (int i4=0;i4<4;i4++){
            const int q0 = qb + grp*16 + i4*4;
            float4 a0 = xm2s[q0],   a1 = xm2s[q0+1];
            float4 a2 = xm2s[q0+2], a3 = xm2s[q0+3];
            float4 sq = *(const float4*)&sqs[q0];
#pragma unroll
            for (int j=0;j<2;j++){
                float d0 = fmaf(a0.x,xp[j].x, fmaf(a0.y,xp[j].y, fmaf(a0.z,xp[j].z, fmaf(a0.w,xp[j].w, sq.x))));
                float d1 = fmaf(a1.x,xp[j].x, fmaf(a1.y,xp[j].y, fmaf(a1.z,xp[j].z, fmaf(a1.w,xp[j].w, sq.y))));
                float d2 = fmaf(a2.x,xp[j].x, fmaf(a2.y,xp[j].y, fmaf(a2.z,xp[j].z, fmaf(a2.w,xp[j].w, sq.z))));
                float d3 = fmaf(a3.x,xp[j].x, fmaf(a3.y,xp[j].y, fmaf(a3.z,xp[j].z, fmaf(a3.w,xp[j].w, sq.w))));
                gm[j] = fminf(gm[j], fminf(fminf(d0,d1), fminf(d2,d3)));
            }
        }
#pragma unroll
        for (int j=0;j<2;j++){
            unsigned u = mmap32(gm[j]);
            unsigned r = (u >> 16) + ((u & 0xFFFFu) ? 1u : 0u);  // round UP
            r = umin_(r, 0xFFFFu);
            gmp16[wu*4 + grp][lane + 64*j] = (ushort)r;
        }
    }
    __syncthreads();

    // ---- selection: 2 threads per target (even/odd group rows), exact top-6 ----
    uint64_t B[6];
#pragma unroll
    for (int j2=0;j2<6;j2++) B[j2] = ~0ull;
    if (t < 256){
        const int tgt = t >> 1, m = t & 1;
        const int pt = tbase + tgt;                 // local node id of target
        unsigned Tc;
        {   // scoped: free the 7-slot cascade before the scan loop
            unsigned M0=~0u,M1=~0u,M2=~0u,M3=~0u,M4=~0u,M5=~0u,M6=~0u;
#pragma unroll
            for (int r=0;r<32;r++){
                unsigned v = gmp16[r][tgt];
                INS7U(v);
            }
            Tc = M6;
        }
        float4 xmq = xm2s[pt];
        float4 xq = make_float4(-0.5f*xmq.x, -0.5f*xmq.y, -0.5f*xmq.z, -0.5f*xmq.w);
#pragma unroll 1
        for (int r=m; r<32; r+=2){
            if ((unsigned)gmp16[r][tgt] <= Tc){
                const int base = r*16;
#pragma unroll 4
                for (int c=0;c<16;c++){
                    const int idx = base + c;
                    float4 a = xm2s[idx];
                    float d = fmaf(a.x,xq.x, fmaf(a.y,xq.y, fmaf(a.z,xq.z, fmaf(a.w,xq.w, sqs[idx]))));
                    uint64_t key = ((uint64_t)mmap32(d) << 32) | (unsigned)idx;
                    key |= (uint64_t)0 - (uint64_t)(idx == pt);   // self -> all-ones
                    if (key < B[0]) cas6_u64(B, key);
                }
            }
        }
        if (m == 1){
#pragma unroll
            for (int j2=0;j2<6;j2++) pairbuf[tgt][j2] = B[j2];
        }
    }
    __syncthreads();
    if (t < 256 && (t & 1) == 0){
        const int tgt = t >> 1;
#pragma unroll
        for (int j2=0;j2<6;j2++){
            uint64_t key = pairbuf[tgt][j2];
            if (key < B[0]) cas6_u64(B, key);
        }
#pragma unroll
        for (int j2=0;j2<6;j2++)
            knn_idx[j2*NN + gbase + tbase + tgt] = (int)(B[j2] & 0xFFFFFFFFull);
    }
}

__global__ __launch_bounds__(512) void graph_kernel(
    const float* __restrict__ x,
    const int* __restrict__ knn_idx,
    const float* __restrict__ bn_part,
    const float* __restrict__ pre_W1, const float* __restrict__ pre_b1, const float* __restrict__ pre_a1,
    const float* __restrict__ pre_W2, const float* __restrict__ pre_b2, const float* __restrict__ pre_a2,
    const float* __restrict__ bn_g, const float* __restrict__ bn_b,
    const float* __restrict__ act_a,
    const float* __restrict__ conv_Wm, const float* __restrict__ conv_bm,
    const float* __restrict__ hlv_W1, const float* __restrict__ hlv_b1,
    const float* __restrict__ hlv_W2, const float* __restrict__ hlv_b2,
    float* __restrict__ out)
{
    __shared__ float4 hbuf[PP];
    __shared__ float wred[8][4];
    __shared__ float pooled[20];
    __shared__ float stats[8];   // 0..3 mu, 4..7 invstd
    __shared__ float hid[20];
    const int g = blockIdx.x, p = threadIdx.x;
    const int gp = g*PP + p;

    // global BN stat reduction (2KB, L2-hot)
    if (p < 64){
        int vv = p>>3, j = p&7;
        float acc = 0.0f;
        for (int i=j;i<GG;i+=8) acc += bn_part[vv*GG + i];
        acc += __shfl_xor(acc,1); acc += __shfl_xor(acc,2); acc += __shfl_xor(acc,4);
        if (j==0) stats[vv] = acc;
    }
    __syncthreads();
    if (p < 4){
        float mu  = stats[p]   * (1.0f/NN);
        float var = stats[4+p] * (1.0f/NN) - mu*mu;
        stats[p]   = mu;
        stats[4+p] = 1.0f / sqrtf(var + 1e-5f);
    }

    float4 xt = ((const float4*)x)[gp];
    float h1[FF], h2[FF];
#pragma unroll
    for (int fo=0;fo<FF;fo++){
        float m = xt.x*pre_W1[0*FF+fo] + xt.y*pre_W1[1*FF+fo]
                + xt.z*pre_W1[2*FF+fo] + xt.w*pre_W1[3*FF+fo] + pre_b1[fo];
        h1[fo] = m >= 0.0f ? m : pre_a1[fo]*m;
    }
#pragma unroll
    for (int fo=0;fo<FF;fo++){
        float m = h1[0]*pre_W2[0*FF+fo] + h1[1]*pre_W2[1*FF+fo]
                + h1[2]*pre_W2[2*FF+fo] + h1[3]*pre_W2[3*FF+fo] + pre_b2[fo];
        h2[fo] = m >= 0.0f ? m : pre_a2[fo]*m;
    }
    __syncthreads();   // stats ready

    float hp[4];
#pragma unroll
    for (int f=0;f<4;f++)
        hp[f] = (h2[f] - stats[f]) * stats[4+f] * bn_g[f] + bn_b[f];
    hbuf[p] = make_float4(hp[0],hp[1],hp[2],hp[3]);
    int nb[KK];
#pragma unroll
    for (int j=0;j<KK;j++) nb[j] = knn_idx[j*NN + gp];

    auto block_accum = [&](const float* h, int slice){
        float v0=h[0], v1=h[1], v2=h[2], v3=h[3];
#pragma unroll
        for (int off=32; off; off>>=1){
            v0 += __shfl_down(v0,off); v1 += __shfl_down(v1,off);
            v2 += __shfl_down(v2,off); v3 += __shfl_down(v3,off);
        }
        int w = p>>6;
        if ((p&63)==0){ wred[w][0]=v0; wred[w][1]=v1; wred[w][2]=v2; wred[w][3]=v3; }
        __syncthreads();
        if (p < 4){
            float a=0;
#pragma unroll
            for (int w2=0;w2<8;w2++) a += wred[w2][p];
            pooled[slice*4+p] = a;
        }
        __syncthreads();
    };

    block_accum(hp, 0);

#pragma unroll 1
    for (int L=0; L<4; L++){
        float4 sm = make_float4(0.f,0.f,0.f,0.f);
#pragma unroll
        for (int j=0;j<KK;j++){
            float4 hn = hbuf[nb[j]];
            sm.x+=hn.x; sm.y+=hn.y; sm.z+=hn.z; sm.w+=hn.w;
        }
        const float* W  = conv_Wm + L*16;
        const float* bm = conv_bm + L*4;
        float nh[4];
#pragma unroll
        for (int fo=0;fo<4;fo++){
            float m = sm.x*W[0*4+fo] + sm.y*W[1*4+fo] + sm.z*W[2*4+fo] + sm.w*W[3*4+fo]
                    + 6.0f*bm[fo] + hp[fo];
            float a = act_a[fo];
            nh[fo] = m >= 0.0f ? m : a*m;
        }
        __syncthreads();
        hbuf[p] = make_float4(nh[0],nh[1],nh[2],nh[3]);
#pragma unroll
        for (int f=0;f<4;f++) hp[f]=nh[f];
        block_accum(hp, L+1);
    }

    if (p < 20){
        float acc = hlv_b1[p];
#pragma unroll 1
        for (int k2=0;k2<20;k2++) acc += pooled[k2]*hlv_W1[k2*20+p];
        hid[p] = acc > 0.0f ? acc : 0.0f;
    }
    __syncthreads();
    if (p == 0){
        float o = hlv_b2[0];
#pragma unroll 1
        for (int j=0;j<20;j++) o += hid[j]*hlv_W2[j];
        out[g] = o;
    }
}

extern "C" void kernel_launch(void* const* d_in, const int* in_sizes, int n_in,
                              void* d_out, int out_size, void* d_ws, size_t ws_size,
                              hipStream_t stream)
{
    const float* x      = (const float*)d_in[0];
    const float* pre_W1 = (const float*)d_in[2];
    const float* pre_b1 = (const float*)d_in[3];
    const float* pre_a1 = (const float*)d_in[4];
    const float* pre_W2 = (const float*)d_in[5];
    const float* pre_b2 = (const float*)d_in[6];
    const float* pre_a2 = (const float*)d_in[7];
    const float* bn_g   = (const float*)d_in[8];
    const float* bn_b   = (const float*)d_in[9];
    const float* act_a  = (const float*)d_in[10];
    const float* conv_Wm= (const float*)d_in[11];
    const float* conv_bm= (const float*)d_in[12];
    const float* hlv_W1 = (const float*)d_in[13];
    const float* hlv_b1 = (const float*)d_in[14];
    const float* hlv_W2 = (const float*)d_in[15];
    const float* hlv_b2 = (const float*)d_in[16];

    char* ws = (char*)d_ws;
    int*   knn     = (int*)ws;                                  // 3 MB
    float* bn_part = (float*)(ws + (size_t)6*NN*sizeof(int));   // 8 KB

    scan_kernel<<<GG*4, PP, 0, stream>>>(x, pre_W1,pre_b1,pre_a1,
                                         pre_W2,pre_b2,pre_a2, bn_part, knn);
    graph_kernel<<<GG, PP, 0, stream>>>(x, knn, bn_part,
                                        pre_W1,pre_b1,pre_a1, pre_W2,pre_b2,pre_a2,
                                        bn_g,bn_b, act_a, conv_Wm,conv_bm,
                                        hlv_W1,hlv_b1,hlv_W2,hlv_b2,
                                        (float*)d_out);
}

// Round 11
// 63.027 us; speedup vs baseline: 2.7466x; 2.7466x over previous
//
#include <hip/hip_runtime.h>

#define GG 256
#define PP 512
#define FF 4
#define KK 6
#define NN (GG*PP)

__device__ __forceinline__ unsigned umin_(unsigned a, unsigned b){ return a<b?a:b; }
__device__ __forceinline__ unsigned umax_(unsigned a, unsigned b){ return a>b?a:b; }
__device__ __forceinline__ float finf(){ return __int_as_float(0x7f800000); }

// monotone (order-preserving) map fp32 -> u32 (all non-NaN)
__device__ __forceinline__ unsigned mmap32(float d){
    int bb = __float_as_int(d);
    int t = bb >> 31;
    return (unsigned)(bb ^ (t | (int)0x80000000));
}

// u64 sorted-desc cascade (B[0] = worst of 6). Caller guarantees kv < B[0].
__device__ __forceinline__ void cas6_u64(uint64_t (&B)[6], uint64_t kv)
{
    bool c1 = kv < B[1]; bool c2 = kv < B[2]; bool c3 = kv < B[3];
    bool c4 = kv < B[4]; bool c5 = kv < B[5];
    B[0] = c1 ? B[1] : kv;
    B[1] = c2 ? B[2] : (c1 ? kv : B[1]);
    B[2] = c3 ? B[3] : (c2 ? kv : B[2]);
    B[3] = c4 ? B[4] : (c3 ? kv : B[3]);
    B[4] = c5 ? B[5] : (c4 ? kv : B[4]);
    B[5] = c5 ? kv : B[5];
}

// ascending 7-slot branchless insert on u32
#define INS7U(v){                                  \
    unsigned n0=umin_(M0,(v));                     \
    unsigned n1=umin_(M1,umax_((v),M0));           \
    unsigned n2=umin_(M2,umax_((v),M1));           \
    unsigned n3=umin_(M3,umax_((v),M2));           \
    unsigned n4=umin_(M4,umax_((v),M3));           \
    unsigned n5=umin_(M5,umax_((v),M4));           \
    unsigned n6=umin_(M6,umax_((v),M5));           \
    M0=n0;M1=n1;M2=n2;M3=n3;M4=n4;M5=n5;M6=n6; }

__global__ __launch_bounds__(512, 4) void scan_kernel(
    const float* __restrict__ x,
    const float* __restrict__ pre_W1, const float* __restrict__ pre_b1, const float* __restrict__ pre_a1,
    const float* __restrict__ pre_W2, const float* __restrict__ pre_b2, const float* __restrict__ pre_a2,
    float* __restrict__ bn_part,     // [8][G]
    int* __restrict__ knn_idx)       // [K][N]
{
    __shared__ float4   xm2s[PP];        // -2*x      (8 KB)
    __shared__ float    sqs[PP];         // |x|^2     (2 KB)
    __shared__ unsigned ubuf[16*128];    // union: gmp16[32][128] / mbuf[16][128] (8 KB)
    __shared__ float    Tv[128];         // per-target threshold (512 B)
    __shared__ uint64_t pairbuf[128][6]; // odd-part partial top-6 (6 KB)
    __shared__ float    wred[8][8];

    ushort   (*gmp16)[128] = (ushort  (*)[128])ubuf;
    unsigned (*mbuf)[128]  = (unsigned(*)[128])ubuf;

    const int t = threadIdx.x;
    const int bid = blockIdx.x;
    const int g = bid >> 2, quarter = bid & 3;   // 4 blocks per graph
    const int tbase = quarter * 128;             // this block's 128 targets
    const int gbase = g * PP;
    const int w = t >> 6, lane = t & 63;
    const int wu = __builtin_amdgcn_readfirstlane(w);   // scanner id (wave-uniform)
    const int qb = wu * 64;                             // candidate base

    // ---- stage graph (+ BN partials on quarter-0 blocks) ----
    float4 xt = ((const float4*)x)[gbase + t];
    xm2s[t] = make_float4(-2.0f*xt.x, -2.0f*xt.y, -2.0f*xt.z, -2.0f*xt.w);
    sqs[t]  = xt.x*xt.x + xt.y*xt.y + xt.z*xt.z + xt.w*xt.w;
    if (quarter == 0){
        float h1[FF], h2[FF];
#pragma unroll
        for (int fo=0;fo<FF;fo++){
            float m = xt.x*pre_W1[0*FF+fo] + xt.y*pre_W1[1*FF+fo]
                    + xt.z*pre_W1[2*FF+fo] + xt.w*pre_W1[3*FF+fo] + pre_b1[fo];
            h1[fo] = m >= 0.0f ? m : pre_a1[fo]*m;
        }
#pragma unroll
        for (int fo=0;fo<FF;fo++){
            float m = h1[0]*pre_W2[0*FF+fo] + h1[1]*pre_W2[1*FF+fo]
                    + h1[2]*pre_W2[2*FF+fo] + h1[3]*pre_W2[3*FF+fo] + pre_b2[fo];
            h2[fo] = m >= 0.0f ? m : pre_a2[fo]*m;
        }
        float v[8];
#pragma unroll
        for (int f=0;f<4;f++){ v[f]=h2[f]; v[4+f]=h2[f]*h2[f]; }
#pragma unroll
        for (int off=32; off; off>>=1){
#pragma unroll
            for (int f=0;f<8;f++) v[f] += __shfl_down(v[f], off);
        }
        if (lane==0){
#pragma unroll
            for (int f=0;f<8;f++) wred[w][f]=v[f];
        }
    }
    __syncthreads();
    if (quarter == 0 && t < 8){
        float a=0;
#pragma unroll
        for (int w2=0;w2<8;w2++) a += wred[w2][t];
        bn_part[t*GG + g] = a;
    }

    // ---- 2 targets per thread in registers (lt = lane + 64j) ----
    float4 xp[2];
#pragma unroll
    for (int j=0;j<2;j++){
        float4 v = xm2s[tbase + lane + 64*j];
        xp[j] = make_float4(-0.5f*v.x, -0.5f*v.y, -0.5f*v.z, -0.5f*v.w);
    }
    const float INF = finf();

    // ---- phase 1: group minima (4 groups of 16 cands per scanner) ----
    // shifted d = |q|^2 - 2 q.p ; self = -|p|^2 = strict global min (no self test)
#pragma unroll 1
    for (int grp=0; grp<4; grp++){
        float gm[2];
        gm[0]=INF; gm[1]=INF;
#pragma unroll
        for (int i4=0;i4<4;i4++){
            const int q0 = qb + grp*16 + i4*4;
            float4 a0 = xm2s[q0],   a1 = xm2s[q0+1];
            float4 a2 = xm2s[q0+2], a3 = xm2s[q0+3];
            float4 sq = *(const float4*)&sqs[q0];
#pragma unroll
            for (int j=0;j<2;j++){
                float d0 = fmaf(a0.x,xp[j].x, fmaf(a0.y,xp[j].y, fmaf(a0.z,xp[j].z, fmaf(a0.w,xp[j].w, sq.x))));
                float d1 = fmaf(a1.x,xp[j].x, fmaf(a1.y,xp[j].y, fmaf(a1.z,xp[j].z, fmaf(a1.w,xp[j].w, sq.y))));
                float d2 = fmaf(a2.x,xp[j].x, fmaf(a2.y,xp[j].y, fmaf(a2.z,xp[j].z, fmaf(a2.w,xp[j].w, sq.z))));
                float d3 = fmaf(a3.x,xp[j].x, fmaf(a3.y,xp[j].y, fmaf(a3.z,xp[j].z, fmaf(a3.w,xp[j].w, sq.w))));
                gm[j] = fminf(gm[j], fminf(fminf(d0,d1), fminf(d2,d3)));
            }
        }
#pragma unroll
        for (int j=0;j<2;j++){
            unsigned u = mmap32(gm[j]);
            unsigned r = (u >> 16) + ((u & 0xFFFFu) ? 1u : 0u);  // round UP
            r = umin_(r, 0xFFFFu);
            gmp16[wu*4 + grp][lane + 64*j] = (ushort)r;
        }
    }
    __syncthreads();

    // ---- merge: T = 7th smallest of 32 group-mins (one thread per target) ----
    if (t < 128){
        unsigned M0=~0u,M1=~0u,M2=~0u,M3=~0u,M4=~0u,M5=~0u,M6=~0u;
#pragma unroll
        for (int r=0;r<32;r++){
            unsigned v = gmp16[r][t];
            INS7U(v);
        }
        unsigned Tc = M6 << 16;
        Tv[t] = (Tc & 0x80000000u) ? __uint_as_float(Tc ^ 0x80000000u)
                                   : __uint_as_float(~Tc);
    }
    __syncthreads();          // gmp16 dead from here; ubuf reused as mbuf

    // ---- phase 2: branchless hit masks (bit 31-k = cand k of 32-cand half) ----
    {
        float Tf[2];
#pragma unroll
        for (int j=0;j<2;j++) Tf[j] = Tv[lane + 64*j];

#pragma unroll 1
        for (int h=0; h<2; h++){
            unsigned m[2];
            m[0]=0; m[1]=0;
#pragma unroll 2
            for (int i4=0;i4<8;i4++){
                const int q0 = qb + h*32 + i4*4;
                float4 a0 = xm2s[q0],   a1 = xm2s[q0+1];
                float4 a2 = xm2s[q0+2], a3 = xm2s[q0+3];
                float4 sq = *(const float4*)&sqs[q0];
#pragma unroll
                for (int j=0;j<2;j++){
                    float d0 = fmaf(a0.x,xp[j].x, fmaf(a0.y,xp[j].y, fmaf(a0.z,xp[j].z, fmaf(a0.w,xp[j].w, sq.x))));
                    float d1 = fmaf(a1.x,xp[j].x, fmaf(a1.y,xp[j].y, fmaf(a1.z,xp[j].z, fmaf(a1.w,xp[j].w, sq.y))));
                    float d2 = fmaf(a2.x,xp[j].x, fmaf(a2.y,xp[j].y, fmaf(a2.z,xp[j].z, fmaf(a2.w,xp[j].w, sq.z))));
                    float d3 = fmaf(a3.x,xp[j].x, fmaf(a3.y,xp[j].y, fmaf(a3.z,xp[j].z, fmaf(a3.w,xp[j].w, sq.w))));
                    unsigned mm = m[j];
                    mm = mm + mm + (d0 <= Tf[j] ? 1u : 0u);
                    mm = mm + mm + (d1 <= Tf[j] ? 1u : 0u);
                    mm = mm + mm + (d2 <= Tf[j] ? 1u : 0u);
                    mm = mm + mm + (d3 <= Tf[j] ? 1u : 0u);
                    m[j] = mm;
                }
            }
#pragma unroll
            for (int j=0;j<2;j++) mbuf[wu*2 + h][lane + 64*j] = m[j];
        }
    }
    __syncthreads();

    // ---- selection: 2 threads per target (even/odd mask rows), exact top-6 ----
    uint64_t B[6];
#pragma unroll
    for (int j2=0;j2<6;j2++) B[j2] = ~0ull;
    if (t < 256){
        const int tgt = t >> 1, par = t & 1;
        const int pt = tbase + tgt;                 // local node id of target
        float4 xmq = xm2s[pt];
        float4 xq = make_float4(-0.5f*xmq.x, -0.5f*xmq.y, -0.5f*xmq.z, -0.5f*xmq.w);
#pragma unroll 1
        for (int r=par; r<16; r+=2){
            unsigned m = mbuf[r][tgt];
            const int base = (r>>1)*64 + (r&1)*32;
            while (m){
                int c = __builtin_clz(m);          // cand k at bit 31-k
                m &= ~(0x80000000u >> c);
                int idx = base + c;
                float4 a = xm2s[idx];
                float d = fmaf(a.x,xq.x, fmaf(a.y,xq.y, fmaf(a.z,xq.z, fmaf(a.w,xq.w, sqs[idx]))));
                uint64_t key = ((uint64_t)mmap32(d) << 32) | (unsigned)idx;
                key |= (uint64_t)0 - (uint64_t)(idx == pt);   // self -> all-ones
                if (key < B[0]) cas6_u64(B, key);
            }
        }
        if (par == 1){
#pragma unroll
            for (int j2=0;j2<6;j2++) pairbuf[tgt][j2] = B[j2];
        }
    }
    __syncthreads();
    if (t < 256 && (t & 1) == 0){
        const int tgt = t >> 1;
#pragma unroll
        for (int j2=0;j2<6;j2++){
            uint64_t key = pairbuf[tgt][j2];
            if (key < B[0]) cas6_u64(B, key);
        }
#pragma unroll
        for (int j2=0;j2<6;j2++)
            knn_idx[j2*NN + gbase + tbase + tgt] = (int)(B[j2] & 0xFFFFFFFFull);
    }
}

__global__ __launch_bounds__(512) void graph_kernel(
    const float* __restrict__ x,
    const int* __restrict__ knn_idx,
    const float* __restrict__ bn_part,
    const float* __restrict__ pre_W1, const float* __restrict__ pre_b1, const float* __restrict__ pre_a1,
    const float* __restrict__ pre_W2, const float* __restrict__ pre_b2, const float* __restrict__ pre_a2,
    const float* __restrict__ bn_g, const float* __restrict__ bn_b,
    const float* __restrict__ act_a,
    const float* __restrict__ conv_Wm, const float* __restrict__ conv_bm,
    const float* __restrict__ hlv_W1, const float* __restrict__ hlv_b1,
    const float* __restrict__ hlv_W2, const float* __restrict__ hlv_b2,
    float* __restrict__ out)
{
    __shared__ float4 hbuf[PP];
    __shared__ float wred[8][4];
    __shared__ float pooled[20];
    __shared__ float stats[8];   // 0..3 mu, 4..7 invstd
    __shared__ float hid[20];
    const int g = blockIdx.x, p = threadIdx.x;
    const int gp = g*PP + p;

    // global BN stat reduction (2KB, L2-hot)
    if (p < 64){
        int vv = p>>3, j = p&7;
        float acc = 0.0f;
        for (int i=j;i<GG;i+=8) acc += bn_part[vv*GG + i];
        acc += __shfl_xor(acc,1); acc += __shfl_xor(acc,2); acc += __shfl_xor(acc,4);
        if (j==0) stats[vv] = acc;
    }
    __syncthreads();
    if (p < 4){
        float mu  = stats[p]   * (1.0f/NN);
        float var = stats[4+p] * (1.0f/NN) - mu*mu;
        stats[p]   = mu;
        stats[4+p] = 1.0f / sqrtf(var + 1e-5f);
    }

    float4 xt = ((const float4*)x)[gp];
    float h1[FF], h2[FF];
#pragma unroll
    for (int fo=0;fo<FF;fo++){
        float m = xt.x*pre_W1[0*FF+fo] + xt.y*pre_W1[1*FF+fo]
                + xt.z*pre_W1[2*FF+fo] + xt.w*pre_W1[3*FF+fo] + pre_b1[fo];
        h1[fo] = m >= 0.0f ? m : pre_a1[fo]*m;
    }
#pragma unroll
    for (int fo=0;fo<FF;fo++){
        float m = h1[0]*pre_W2[0*FF+fo] + h1[1]*pre_W2[1*FF+fo]
                + h1[2]*pre_W2[2*FF+fo] + h1[3]*pre_W2[3*FF+fo] + pre_b2[fo];
        h2[fo] = m >= 0.0f ? m : pre_a2[fo]*m;
    }
    __syncthreads();   // stats ready

    float hp[4];
#pragma unroll
    for (int f=0;f<4;f++)
        hp[f] = (h2[f] - stats[f]) * stats[4+f] * bn_g[f] + bn_b[f];
    hbuf[p] = make_float4(hp[0],hp[1],hp[2],hp[3]);
    int nb[KK];
#pragma unroll
    for (int j=0;j<KK;j++) nb[j] = knn_idx[j*NN + gp];

    auto block_accum = [&](const float* h, int slice){
        float v0=h[0], v1=h[1], v2=h[2], v3=h[3];
#pragma unroll
        for (int off=32; off; off>>=1){
            v0 += __shfl_down(v0,off); v1 += __shfl_down(v1,off);
            v2 += __shfl_down(v2,off); v3 += __shfl_down(v3,off);
        }
        int w = p>>6;
        if ((p&63)==0){ wred[w][0]=v0; wred[w][1]=v1; wred[w][2]=v2; wred[w][3]=v3; }
        __syncthreads();
        if (p < 4){
            float a=0;
#pragma unroll
            for (int w2=0;w2<8;w2++) a += wred[w2][p];
            pooled[slice*4+p] = a;
        }
        __syncthreads();
    };

    block_accum(hp, 0);

#pragma unroll 1
    for (int L=0; L<4; L++){
        float4 sm = make_float4(0.f,0.f,0.f,0.f);
#pragma unroll
        for (int j=0;j<KK;j++){
            float4 hn = hbuf[nb[j]];
            sm.x+=hn.x; sm.y+=hn.y; sm.z+=hn.z; sm.w+=hn.w;
        }
        const float* W  = conv_Wm + L*16;
        const float* bm = conv_bm + L*4;
        float nh[4];
#pragma unroll
        for (int fo=0;fo<4;fo++){
            float m = sm.x*W[0*4+fo] + sm.y*W[1*4+fo] + sm.z*W[2*4+fo] + sm.w*W[3*4+fo]
                    + 6.0f*bm[fo] + hp[fo];
            float a = act_a[fo];
            nh[fo] = m >= 0.0f ? m : a*m;
        }
        __syncthreads();
        hbuf[p] = make_float4(nh[0],nh[1],nh[2],nh[3]);
#pragma unroll
        for (int f=0;f<4;f++) hp[f]=nh[f];
        block_accum(hp, L+1);
    }

    if (p < 20){
        float acc = hlv_b1[p];
#pragma unroll 1
        for (int k2=0;k2<20;k2++) acc += pooled[k2]*hlv_W1[k2*20+p];
        hid[p] = acc > 0.0f ? acc : 0.0f;
    }
    __syncthreads();
    if (p == 0){
        float o = hlv_b2[0];
#pragma unroll 1
        for (int j=0;j<20;j++) o += hid[j]*hlv_W2[j];
        out[g] = o;
    }
}

extern "C" void kernel_launch(void* const* d_in, const int* in_sizes, int n_in,
                              void* d_out, int out_size, void* d_ws, size_t ws_size,
                              hipStream_t stream)
{
    const float* x      = (const float*)d_in[0];
    const float* pre_W1 = (const float*)d_in[2];
    const float* pre_b1 = (const float*)d_in[3];
    const float* pre_a1 = (const float*)d_in[4];
    const float* pre_W2 = (const float*)d_in[5];
    const float* pre_b2 = (const float*)d_in[6];
    const float* pre_a2 = (const float*)d_in[7];
    const float* bn_g   = (const float*)d_in[8];
    const float* bn_b   = (const float*)d_in[9];
    const float* act_a  = (const float*)d_in[10];
    const float* conv_Wm= (const float*)d_in[11];
    const float* conv_bm= (const float*)d_in[12];
    const float* hlv_W1 = (const float*)d_in[13];
    const float* hlv_b1 = (const float*)d_in[14];
    const float* hlv_W2 = (const float*)d_in[15];
    const float* hlv_b2 = (const float*)d_in[16];

    char* ws = (char*)d_ws;
    int*   knn     = (int*)ws;                                  // 3 MB
    float* bn_part = (float*)(ws + (size_t)6*NN*sizeof(int));   // 8 KB

    scan_kernel<<<GG*4, PP, 0, stream>>>(x, pre_W1,pre_b1,pre_a1,
                                         pre_W2,pre_b2,pre_a2, bn_part, knn);
    graph_kernel<<<GG, PP, 0, stream>>>(x, knn, bn_part,
                                        pre_W1,pre_b1,pre_a1, pre_W2,pre_b2,pre_a2,
                                        bn_g,bn_b, act_a, conv_Wm,conv_bm,
                                        hlv_W1,hlv_b1,hlv_W2,hlv_b2,
                                        (float*)d_out);
}

// Round 12
// 56.468 us; speedup vs baseline: 3.0656x; 1.1161x over previous
//
#include <hip/hip_runtime.h>

#define GG 256
#define PP 512
#define FF 4
#define KK 6
#define NN (GG*PP)

__device__ __forceinline__ unsigned umin_(unsigned a, unsigned b){ return a<b?a:b; }
__device__ __forceinline__ unsigned umax_(unsigned a, unsigned b){ return a>b?a:b; }
__device__ __forceinline__ float finf(){ return __int_as_float(0x7f800000); }

// monotone (order-preserving) map fp32 -> u32 (all non-NaN)
__device__ __forceinline__ unsigned mmap32(float d){
    int bb = __float_as_int(d);
    int t = bb >> 31;
    return (unsigned)(bb ^ (t | (int)0x80000000));
}

// u64 sorted-desc cascade (B[0] = worst of 6). Caller guarantees kv < B[0].
__device__ __forceinline__ void cas6_u64(uint64_t (&B)[6], uint64_t kv)
{
    bool c1 = kv < B[1]; bool c2 = kv < B[2]; bool c3 = kv < B[3];
    bool c4 = kv < B[4]; bool c5 = kv < B[5];
    B[0] = c1 ? B[1] : kv;
    B[1] = c2 ? B[2] : (c1 ? kv : B[1]);
    B[2] = c3 ? B[3] : (c2 ? kv : B[2]);
    B[3] = c4 ? B[4] : (c3 ? kv : B[3]);
    B[4] = c5 ? B[5] : (c4 ? kv : B[4]);
    B[5] = c5 ? kv : B[5];
}

// ascending 7-slot branchless insert on u32
#define INS7U(v){                                  \
    unsigned n0=umin_(M0,(v));                     \
    unsigned n1=umin_(M1,umax_((v),M0));           \
    unsigned n2=umin_(M2,umax_((v),M1));           \
    unsigned n3=umin_(M3,umax_((v),M2));           \
    unsigned n4=umin_(M4,umax_((v),M3));           \
    unsigned n5=umin_(M5,umax_((v),M4));           \
    unsigned n6=umin_(M6,umax_((v),M5));           \
    M0=n0;M1=n1;M2=n2;M3=n3;M4=n4;M5=n5;M6=n6; }

__global__ __launch_bounds__(512, 4) void scan_kernel(
    const float* __restrict__ x,
    const float* __restrict__ pre_W1, const float* __restrict__ pre_b1, const float* __restrict__ pre_a1,
    const float* __restrict__ pre_W2, const float* __restrict__ pre_b2, const float* __restrict__ pre_a2,
    float* __restrict__ bn_part,     // [8][G]
    int* __restrict__ knn_idx)       // [K][N]
{
    __shared__ float4   xm2s[PP];        // -2*x      (8 KB)
    __shared__ float    sqs[PP];         // |x|^2     (2 KB)
    __shared__ unsigned ubuf[16*128];    // union: gmp16[32][128] u16 / mbuf[16][128] u32 (8 KB)
    __shared__ float    Tv[128];         // per-target threshold (512 B)
    __shared__ uint64_t pairbuf[128][6]; // odd-part partial top-6 (6 KB)
    __shared__ float    wred[8][8];

    ushort   (*gmp16)[128] = (ushort  (*)[128])ubuf;
    unsigned (*mbuf)[128]  = (unsigned(*)[128])ubuf;

    const int t = threadIdx.x;
    const int bid = blockIdx.x;
    const int g = bid >> 2, quarter = bid & 3;   // 4 blocks per graph
    const int tbase = quarter * 128;             // this block's 128 targets
    const int gbase = g * PP;
    const int w = t >> 6, lane = t & 63;
    const int sid = w*2 + (lane >> 5);           // 16 scanners x 32 cands
    const int qb = sid * 32;                     // candidate base (2 addrs/wave)
    const int tcol = t & 31;                     // target column (4 targets/lane)

    // ---- stage graph (+ BN partials on quarter-0 blocks) ----
    float4 xt = ((const float4*)x)[gbase + t];
    xm2s[t] = make_float4(-2.0f*xt.x, -2.0f*xt.y, -2.0f*xt.z, -2.0f*xt.w);
    sqs[t]  = xt.x*xt.x + xt.y*xt.y + xt.z*xt.z + xt.w*xt.w;
    if (quarter == 0){
        float h1[FF], h2[FF];
#pragma unroll
        for (int fo=0;fo<FF;fo++){
            float m = xt.x*pre_W1[0*FF+fo] + xt.y*pre_W1[1*FF+fo]
                    + xt.z*pre_W1[2*FF+fo] + xt.w*pre_W1[3*FF+fo] + pre_b1[fo];
            h1[fo] = m >= 0.0f ? m : pre_a1[fo]*m;
        }
#pragma unroll
        for (int fo=0;fo<FF;fo++){
            float m = h1[0]*pre_W2[0*FF+fo] + h1[1]*pre_W2[1*FF+fo]
                    + h1[2]*pre_W2[2*FF+fo] + h1[3]*pre_W2[3*FF+fo] + pre_b2[fo];
            h2[fo] = m >= 0.0f ? m : pre_a2[fo]*m;
        }
        float v[8];
#pragma unroll
        for (int f=0;f<4;f++){ v[f]=h2[f]; v[4+f]=h2[f]*h2[f]; }
#pragma unroll
        for (int off=32; off; off>>=1){
#pragma unroll
            for (int f=0;f<8;f++) v[f] += __shfl_down(v[f], off);
        }
        if (lane==0){
#pragma unroll
            for (int f=0;f<8;f++) wred[w][f]=v[f];
        }
    }
    __syncthreads();
    if (quarter == 0 && t < 8){
        float a=0;
#pragma unroll
        for (int w2=0;w2<8;w2++) a += wred[w2][t];
        bn_part[t*GG + g] = a;
    }

    // ---- 4 targets per lane-half (tgt = tcol + 32j) ----
    float4 xp[4];
#pragma unroll
    for (int j=0;j<4;j++){
        float4 v = xm2s[tbase + tcol + 32*j];
        xp[j] = make_float4(-0.5f*v.x, -0.5f*v.y, -0.5f*v.z, -0.5f*v.w);
    }
    const float INF = finf();

    // ---- phase 1: group minima (2 groups of 16 cands per scanner) ----
    // shifted d = |q|^2 - 2 q.p ; self = -|p|^2 = strict global min (no self test)
#pragma unroll 1
    for (int grp=0; grp<2; grp++){
        float gm[4];
#pragma unroll
        for (int j=0;j<4;j++) gm[j]=INF;
#pragma unroll
        for (int i4=0;i4<4;i4++){
            const int q0 = qb + grp*16 + i4*4;
            float4 a0 = xm2s[q0],   a1 = xm2s[q0+1];
            float4 a2 = xm2s[q0+2], a3 = xm2s[q0+3];
            float4 sq = *(const float4*)&sqs[q0];
#pragma unroll
            for (int j=0;j<4;j++){
                float d0 = fmaf(a0.x,xp[j].x, fmaf(a0.y,xp[j].y, fmaf(a0.z,xp[j].z, fmaf(a0.w,xp[j].w, sq.x))));
                float d1 = fmaf(a1.x,xp[j].x, fmaf(a1.y,xp[j].y, fmaf(a1.z,xp[j].z, fmaf(a1.w,xp[j].w, sq.y))));
                float d2 = fmaf(a2.x,xp[j].x, fmaf(a2.y,xp[j].y, fmaf(a2.z,xp[j].z, fmaf(a2.w,xp[j].w, sq.z))));
                float d3 = fmaf(a3.x,xp[j].x, fmaf(a3.y,xp[j].y, fmaf(a3.z,xp[j].z, fmaf(a3.w,xp[j].w, sq.w))));
                gm[j] = fminf(gm[j], fminf(fminf(d0,d1), fminf(d2,d3)));
            }
        }
#pragma unroll
        for (int j=0;j<4;j++){
            unsigned u = mmap32(gm[j]);
            unsigned r = (u >> 16) + ((u & 0xFFFFu) ? 1u : 0u);  // round UP
            r = umin_(r, 0xFFFFu);
            gmp16[sid*2 + grp][tcol + 32*j] = (ushort)r;
        }
    }
    __syncthreads();

    // ---- merge: T = 7th smallest of 32 group-mins (one thread per target) ----
    if (t < 128){
        unsigned M0=~0u,M1=~0u,M2=~0u,M3=~0u,M4=~0u,M5=~0u,M6=~0u;
#pragma unroll
        for (int r=0;r<32;r++){
            unsigned v = gmp16[r][t];
            INS7U(v);
        }
        unsigned Tc = M6 << 16;
        Tv[t] = (Tc & 0x80000000u) ? __uint_as_float(Tc ^ 0x80000000u)
                                   : __uint_as_float(~Tc);
    }
    __syncthreads();          // gmp16 dead from here; ubuf reused as mbuf

    // ---- phase 2: branchless hit masks (bit 31-k = cand k of scanner) ----
    {
        float Tf[4];
#pragma unroll
        for (int j=0;j<4;j++) Tf[j] = Tv[tcol + 32*j];

        unsigned m[4];
#pragma unroll
        for (int j=0;j<4;j++) m[j]=0;
#pragma unroll 2
        for (int i4=0;i4<8;i4++){
            const int q0 = qb + i4*4;
            float4 a0 = xm2s[q0],   a1 = xm2s[q0+1];
            float4 a2 = xm2s[q0+2], a3 = xm2s[q0+3];
            float4 sq = *(const float4*)&sqs[q0];
#pragma unroll
            for (int j=0;j<4;j++){
                float d0 = fmaf(a0.x,xp[j].x, fmaf(a0.y,xp[j].y, fmaf(a0.z,xp[j].z, fmaf(a0.w,xp[j].w, sq.x))));
                float d1 = fmaf(a1.x,xp[j].x, fmaf(a1.y,xp[j].y, fmaf(a1.z,xp[j].z, fmaf(a1.w,xp[j].w, sq.y))));
                float d2 = fmaf(a2.x,xp[j].x, fmaf(a2.y,xp[j].y, fmaf(a2.z,xp[j].z, fmaf(a2.w,xp[j].w, sq.z))));
                float d3 = fmaf(a3.x,xp[j].x, fmaf(a3.y,xp[j].y, fmaf(a3.z,xp[j].z, fmaf(a3.w,xp[j].w, sq.w))));
                unsigned mm = m[j];
                mm = mm + mm + (d0 <= Tf[j] ? 1u : 0u);
                mm = mm + mm + (d1 <= Tf[j] ? 1u : 0u);
                mm = mm + mm + (d2 <= Tf[j] ? 1u : 0u);
                mm = mm + mm + (d3 <= Tf[j] ? 1u : 0u);
                m[j] = mm;
            }
        }
#pragma unroll
        for (int j=0;j<4;j++) mbuf[sid][tcol + 32*j] = m[j];
    }
    __syncthreads();

    // ---- selection: 2 threads per target (even/odd scanner rows), exact top-6 ----
    uint64_t B[6];
#pragma unroll
    for (int j2=0;j2<6;j2++) B[j2] = ~0ull;
    if (t < 256){
        const int tgt = t >> 1, par = t & 1;
        const int pt = tbase + tgt;                 // local node id of target
        float4 xmq = xm2s[pt];
        float4 xq = make_float4(-0.5f*xmq.x, -0.5f*xmq.y, -0.5f*xmq.z, -0.5f*xmq.w);
#pragma unroll 1
        for (int r=par; r<16; r+=2){
            unsigned m = mbuf[r][tgt];
            const int base = r*32;
            while (m){
                int c = __builtin_clz(m);          // cand k at bit 31-k
                m &= ~(0x80000000u >> c);
                int idx = base + c;
                float4 a = xm2s[idx];
                float d = fmaf(a.x,xq.x, fmaf(a.y,xq.y, fmaf(a.z,xq.z, fmaf(a.w,xq.w, sqs[idx]))));
                uint64_t key = ((uint64_t)mmap32(d) << 32) | (unsigned)idx;
                key |= (uint64_t)0 - (uint64_t)(idx == pt);   // self -> all-ones
                if (key < B[0]) cas6_u64(B, key);
            }
        }
        if (par == 1){
#pragma unroll
            for (int j2=0;j2<6;j2++) pairbuf[tgt][j2] = B[j2];
        }
    }
    __syncthreads();
    if (t < 256 && (t & 1) == 0){
        const int tgt = t >> 1;
#pragma unroll
        for (int j2=0;j2<6;j2++){
            uint64_t key = pairbuf[tgt][j2];
            if (key < B[0]) cas6_u64(B, key);
        }
#pragma unroll
        for (int j2=0;j2<6;j2++)
            knn_idx[j2*NN + gbase + tbase + tgt] = (int)(B[j2] & 0xFFFFFFFFull);
    }
}

__global__ __launch_bounds__(512) void graph_kernel(
    const float* __restrict__ x,
    const int* __restrict__ knn_idx,
    const float* __restrict__ bn_part,
    const float* __restrict__ pre_W1, const float* __restrict__ pre_b1, const float* __restrict__ pre_a1,
    const float* __restrict__ pre_W2, const float* __restrict__ pre_b2, const float* __restrict__ pre_a2,
    const float* __restrict__ bn_g, const float* __restrict__ bn_b,
    const float* __restrict__ act_a,
    const float* __restrict__ conv_Wm, const float* __restrict__ conv_bm,
    const float* __restrict__ hlv_W1, const float* __restrict__ hlv_b1,
    const float* __restrict__ hlv_W2, const float* __restrict__ hlv_b2,
    float* __restrict__ out)
{
    __shared__ float4 hbuf[PP];
    __shared__ float wred[8][4];
    __shared__ float pooled[20];
    __shared__ float stats[8];   // 0..3 mu, 4..7 invstd
    __shared__ float hid[20];
    const int g = blockIdx.x, p = threadIdx.x;
    const int gp = g*PP + p;

    // global BN stat reduction (2KB, L2-hot)
    if (p < 64){
        int vv = p>>3, j = p&7;
        float acc = 0.0f;
        for (int i=j;i<GG;i+=8) acc += bn_part[vv*GG + i];
        acc += __shfl_xor(acc,1); acc += __shfl_xor(acc,2); acc += __shfl_xor(acc,4);
        if (j==0) stats[vv] = acc;
    }
    __syncthreads();
    if (p < 4){
        float mu  = stats[p]   * (1.0f/NN);
        float var = stats[4+p] * (1.0f/NN) - mu*mu;
        stats[p]   = mu;
        stats[4+p] = 1.0f / sqrtf(var + 1e-5f);
    }

    float4 xt = ((const float4*)x)[gp];
    float h1[FF], h2[FF];
#pragma unroll
    for (int fo=0;fo<FF;fo++){
        float m = xt.x*pre_W1[0*FF+fo] + xt.y*pre_W1[1*FF+fo]
                + xt.z*pre_W1[2*FF+fo] + xt.w*pre_W1[3*FF+fo] + pre_b1[fo];
        h1[fo] = m >= 0.0f ? m : pre_a1[fo]*m;
    }
#pragma unroll
    for (int fo=0;fo<FF;fo++){
        float m = h1[0]*pre_W2[0*FF+fo] + h1[1]*pre_W2[1*FF+fo]
                + h1[2]*pre_W2[2*FF+fo] + h1[3]*pre_W2[3*FF+fo] + pre_b2[fo];
        h2[fo] = m >= 0.0f ? m : pre_a2[fo]*m;
    }
    __syncthreads();   // stats ready

    float hp[4];
#pragma unroll
    for (int f=0;f<4;f++)
        hp[f] = (h2[f] - stats[f]) * stats[4+f] * bn_g[f] + bn_b[f];
    hbuf[p] = make_float4(hp[0],hp[1],hp[2],hp[3]);
    int nb[KK];
#pragma unroll
    for (int j=0;j<KK;j++) nb[j] = knn_idx[j*NN + gp];

    auto block_accum = [&](const float* h, int slice){
        float v0=h[0], v1=h[1], v2=h[2], v3=h[3];
#pragma unroll
        for (int off=32; off; off>>=1){
            v0 += __shfl_down(v0,off); v1 += __shfl_down(v1,off);
            v2 += __shfl_down(v2,off); v3 += __shfl_down(v3,off);
        }
        int w = p>>6;
        if ((p&63)==0){ wred[w][0]=v0; wred[w][1]=v1; wred[w][2]=v2; wred[w][3]=v3; }
        __syncthreads();
        if (p < 4){
            float a=0;
#pragma unroll
            for (int w2=0;w2<8;w2++) a += wred[w2][p];
            pooled[slice*4+p] = a;
        }
        __syncthreads();
    };

    block_accum(hp, 0);

#pragma unroll 1
    for (int L=0; L<4; L++){
        float4 sm = make_float4(0.f,0.f,0.f,0.f);
#pragma unroll
        for (int j=0;j<KK;j++){
            float4 hn = hbuf[nb[j]];
            sm.x+=hn.x; sm.y+=hn.y; sm.z+=hn.z; sm.w+=hn.w;
        }
        const float* W  = conv_Wm + L*16;
        const float* bm = conv_bm + L*4;
        float nh[4];
#pragma unroll
        for (int fo=0;fo<4;fo++){
            float m = sm.x*W[0*4+fo] + sm.y*W[1*4+fo] + sm.z*W[2*4+fo] + sm.w*W[3*4+fo]
                    + 6.0f*bm[fo] + hp[fo];
            float a = act_a[fo];
            nh[fo] = m >= 0.0f ? m : a*m;
        }
        __syncthreads();
        hbuf[p] = make_float4(nh[0],nh[1],nh[2],nh[3]);
#pragma unroll
        for (int f=0;f<4;f++) hp[f]=nh[f];
        block_accum(hp, L+1);
    }

    if (p < 20){
        float acc = hlv_b1[p];
#pragma unroll 1
        for (int k2=0;k2<20;k2++) acc += pooled[k2]*hlv_W1[k2*20+p];
        hid[p] = acc > 0.0f ? acc : 0.0f;
    }
    __syncthreads();
    if (p == 0){
        float o = hlv_b2[0];
#pragma unroll 1
        for (int j=0;j<20;j++) o += hid[j]*hlv_W2[j];
        out[g] = o;
    }
}

extern "C" void kernel_launch(void* const* d_in, const int* in_sizes, int n_in,
                              void* d_out, int out_size, void* d_ws, size_t ws_size,
                              hipStream_t stream)
{
    const float* x      = (const float*)d_in[0];
    const float* pre_W1 = (const float*)d_in[2];
    const float* pre_b1 = (const float*)d_in[3];
    const float* pre_a1 = (const float*)d_in[4];
    const float* pre_W2 = (const float*)d_in[5];
    const float* pre_b2 = (const float*)d_in[6];
    const float* pre_a2 = (const float*)d_in[7];
    const float* bn_g   = (const float*)d_in[8];
    const float* bn_b   = (const float*)d_in[9];
    const float* act_a  = (const float*)d_in[10];
    const float* conv_Wm= (const float*)d_in[11];
    const float* conv_bm= (const float*)d_in[12];
    const float* hlv_W1 = (const float*)d_in[13];
    const float* hlv_b1 = (const float*)d_in[14];
    const float* hlv_W2 = (const float*)d_in[15];
    const float* hlv_b2 = (const float*)d_in[16];

    char* ws = (char*)d_ws;
    int*   knn     = (int*)ws;                                  // 3 MB
    float* bn_part = (float*)(ws + (size_t)6*NN*sizeof(int));   // 8 KB

    scan_kernel<<<GG*4, PP, 0, stream>>>(x, pre_W1,pre_b1,pre_a1,
                                         pre_W2,pre_b2,pre_a2, bn_part, knn);
    graph_kernel<<<GG, PP, 0, stream>>>(x, knn, bn_part,
                                        pre_W1,pre_b1,pre_a1, pre_W2,pre_b2,pre_a2,
                                        bn_g,bn_b, act_a, conv_Wm,conv_bm,
                                        hlv_W1,hlv_b1,hlv_W2,hlv_b2,
                                        (float*)d_out);
}